// Round 9
// baseline (791.344 us; speedup 1.0000x reference)
//
#include <hip/hip_runtime.h>

#define N_NODES 100000
#define N_EDGES 1600000
#define MPAD    100096   /* 782 * 128 */
#define MTILES  782

#define NB      391      /* ceil(100000/256) buckets of 256 nodes */
#define CH      8192     /* edges per phase-A block */
#define NBLK_A  196      /* ceil(1600000/8192) */

typedef __attribute__((ext_vector_type(8))) short short8;
typedef __attribute__((ext_vector_type(4))) float f32x4;

static __device__ __forceinline__ unsigned short f2bf(float f) {
  unsigned u = __builtin_bit_cast(unsigned, f);
  u += 0x7fffu + ((u >> 16) & 1u);     // round-to-nearest-even
  return (unsigned short)(u >> 16);
}
static __device__ __forceinline__ float bf2f(unsigned short s) {
  unsigned u = ((unsigned)s) << 16;
  return __builtin_bit_cast(float, u);
}

// ---------------- CSR build: two-level LDS counting sort ----------------

__global__ __launch_bounds__(256) void k_bhist(const int* __restrict__ row,
                                               int* __restrict__ Hc) {
  __shared__ int hist[NB];
  int b = blockIdx.x, t = threadIdx.x;
  for (int j = t; j < NB; j += 256) hist[j] = 0;
  __syncthreads();
  int base = b * CH;
  #pragma unroll
  for (int k = 0; k < 8; ++k) {
    int i = base + k * 1024 + t * 4;
    if (i < N_EDGES) {
      int4 r = *(const int4*)(row + i);
      atomicAdd(&hist[r.x >> 8], 1);
      atomicAdd(&hist[r.y >> 8], 1);
      atomicAdd(&hist[r.z >> 8], 1);
      atomicAdd(&hist[r.w >> 8], 1);
    }
  }
  __syncthreads();
  for (int j = t; j < NB; j += 256) Hc[j * NBLK_A + b] = hist[j];
}

__global__ __launch_bounds__(512) void k_bscan(const int* __restrict__ Hc,
                                               int* __restrict__ Boff) {
  int t = threadIdx.x;
  int total = 0;
  if (t < NB) {
    const int* p = Hc + t * NBLK_A;
    for (int i = 0; i < NBLK_A; i += 4) {
      int4 v = *(const int4*)(p + i);
      total += v.x + v.y + v.z + v.w;
    }
  }
  int lane = t & 63, w = t >> 6;
  int incl = total;
  #pragma unroll
  for (int off = 1; off < 64; off <<= 1) {
    int n = __shfl_up(incl, off, 64);
    if (lane >= off) incl += n;
  }
  __shared__ int ws[8];
  if (lane == 63) ws[w] = incl;
  __syncthreads();
  int wo = 0;
  for (int ww = 0; ww < w; ++ww) wo += ws[ww];
  int excl = wo + incl - total;
  if (t < NB) Boff[t] = excl;
  if (t == NB - 1) Boff[NB] = excl + total;
}

__global__ __launch_bounds__(64) void k_bexp(const int* __restrict__ Hc,
                                             const int* __restrict__ Boff,
                                             int* __restrict__ G) {
  int b = blockIdx.x, l = threadIdx.x;
  int run = Boff[b];
  const int* p = Hc + b * NBLK_A;
  for (int c = 0; c < NBLK_A; c += 64) {
    int idx = c + l;
    int v = (idx < NBLK_A) ? p[idx] : 0;
    int incl = v;
    #pragma unroll
    for (int off = 1; off < 64; off <<= 1) {
      int n = __shfl_up(incl, off, 64);
      if (l >= off) incl += n;
    }
    if (idx < NBLK_A) G[b * NBLK_A + idx] = run + incl - v;
    run += __shfl(incl, 63, 64);
  }
}

__global__ __launch_bounds__(256) void k_bscat(const int* __restrict__ row,
                                               const int* __restrict__ col,
                                               const int* __restrict__ G,
                                               unsigned* __restrict__ tmp) {
  __shared__ int cur[NB];
  int b = blockIdx.x, t = threadIdx.x;
  for (int j = t; j < NB; j += 256) cur[j] = G[j * NBLK_A + b];
  __syncthreads();
  int base = b * CH;
  #pragma unroll
  for (int k = 0; k < 8; ++k) {
    int i = base + k * 1024 + t * 4;
    if (i < N_EDGES) {
      int4 r = *(const int4*)(row + i);
      int4 c = *(const int4*)(col + i);
      int p0 = atomicAdd(&cur[r.x >> 8], 1);
      tmp[p0] = (unsigned)c.x | ((unsigned)(r.x & 255) << 24);
      int p1 = atomicAdd(&cur[r.y >> 8], 1);
      tmp[p1] = (unsigned)c.y | ((unsigned)(r.y & 255) << 24);
      int p2 = atomicAdd(&cur[r.z >> 8], 1);
      tmp[p2] = (unsigned)c.z | ((unsigned)(r.z & 255) << 24);
      int p3 = atomicAdd(&cur[r.w >> 8], 1);
      tmp[p3] = (unsigned)c.w | ((unsigned)(r.w & 255) << 24);
    }
  }
}

__global__ __launch_bounds__(256) void k_bsort(const unsigned* __restrict__ tmp,
                                               const int* __restrict__ Boff,
                                               int* __restrict__ rp,
                                               int* __restrict__ cs) {
  __shared__ int hist[256];
  __shared__ int wsum[4];
  int b = blockIdx.x, t = threadIdx.x;
  int s = Boff[b], e = Boff[b + 1];
  hist[t] = 0;
  __syncthreads();
  for (int i = s + t; i < e; i += 256) atomicAdd(&hist[tmp[i] >> 24], 1);
  __syncthreads();
  int v = hist[t];
  int lane = t & 63, w = t >> 6;
  int incl = v;
  #pragma unroll
  for (int off = 1; off < 64; off <<= 1) {
    int n = __shfl_up(incl, off, 64);
    if (lane >= off) incl += n;
  }
  if (lane == 63) wsum[w] = incl;
  __syncthreads();
  int wo = 0;
  for (int ww = 0; ww < w; ++ww) wo += wsum[ww];
  int excl = s + wo + incl - v;
  int node = (b << 8) + t;
  if (node < N_NODES) rp[node] = excl;
  __syncthreads();
  hist[t] = excl;    // reuse as cursor
  __syncthreads();
  for (int i = s + t; i < e; i += 256) {
    unsigned u = tmp[i];
    int pos = atomicAdd(&hist[u >> 24], 1);
    cs[pos] = (int)(u & 0xFFFFFFu);
  }
  if (b == 0 && t == 0) rp[N_NODES] = N_EDGES;
}

// ---------------- feature conversion / aggregation ----------------

// x f32 -> bf16 into Acat[:,128:256]
__global__ void k_cvt_x(const float* __restrict__ x, short* __restrict__ Acat) {
  int id = blockIdx.x * 256 + threadIdx.x;
  if (id >= N_NODES * 32) return;
  int node = id >> 5, c4 = id & 31;
  float4 v = *(const float4*)(x + (size_t)node * 128 + c4 * 4);
  uint2 u;
  u.x = (unsigned)f2bf(v.x) | ((unsigned)f2bf(v.y) << 16);
  u.y = (unsigned)f2bf(v.z) | ((unsigned)f2bf(v.w) << 16);
  *(uint2*)(Acat + (size_t)node * 256 + 128 + c4 * 4) = u;
}

// Column-partitioned aggregation: block B -> partition p = B&7 (XCD-affine
// under round-robin dispatch), nodes 4*(B>>3).. +3 (one wave each).
// XCD p gathers ONLY column dwords [p*8, p*8+8) of each source row ->
// per-XCD gather working set = 25.6MB/8 = 3.2MB < 4MB L2 -> L2-resident.
// Lane layout: eg = lane>>3 (edge slot), cl = lane&7 (column dword).
// Round = 8 edges, one dword gather per lane; 4-round superrounds keep
// 32 edges in flight. Clamped tail + over*row[last] subtraction (exact);
// cross-eg combine = 3 shfl_xor. cs loads are non-temporal (8x re-read,
// must not evict the resident slice).
// Gathered slice base = shorts GOFF of row; RESID adds src[t,128:256],
// writes f32 to dst_f32; else bf16 to dst_bf.
template <bool RESID, int GOFF>
__global__ __launch_bounds__(256) void k_agg(const int* __restrict__ rp,
                                             const int* __restrict__ cs,
                                             const short* __restrict__ src,
                                             short* __restrict__ dst_bf,
                                             float* __restrict__ dst_f32) {
  const int B = blockIdx.x;
  const int p = B & 7;                          // partition == XCD (heuristic)
  const int t = (B >> 3) * 4 + (threadIdx.x >> 6);
  if (t >= N_NODES) return;
  const int lane = threadIdx.x & 63;
  const int eg = lane >> 3;                     // edge slot 0..7
  const int cl = lane & 7;                      // column dword 0..7
  const int s = rp[t], e = rp[t + 1];
  const int d = e - s;
  float a0 = 0.f, a1 = 0.f;
  const short* gb = src + GOFF + p * 16 + cl * 2;
  if (d > 0) {
    const int last = e - 1;
    const int srounds = (d + 31) >> 5;          // 32 edges per superround
    for (int r = 0; r < srounds; ++r) {
      const int base = s + (r << 5) + eg;
      int cc[4];
      #pragma unroll
      for (int q = 0; q < 4; ++q) {
        int j = base + q * 8;
        j = (j < last) ? j : last;
        cc[q] = __builtin_nontemporal_load(cs + j);
      }
      unsigned uu[4];
      #pragma unroll
      for (int q = 0; q < 4; ++q)
        uu[q] = *(const unsigned*)(gb + (size_t)cc[q] * 256);
      #pragma unroll
      for (int q = 0; q < 4; ++q) {
        a0 += bf2f((unsigned short)uu[q]);
        a1 += bf2f((unsigned short)(uu[q] >> 16));
      }
    }
    // combine the 8 edge-slot partials (bits 3,4,5 of lane)
    a0 += __shfl_xor(a0, 8);  a1 += __shfl_xor(a1, 8);
    a0 += __shfl_xor(a0, 16); a1 += __shfl_xor(a1, 16);
    a0 += __shfl_xor(a0, 32); a1 += __shfl_xor(a1, 32);
    const int over = (srounds << 5) - d;        // 0..31 extra reads of row[last]
    if (over) {
      unsigned ul = *(const unsigned*)(gb + (size_t)cs[last] * 256);
      float c = (float)over;
      a0 -= c * bf2f((unsigned short)ul);
      a1 -= c * bf2f((unsigned short)(ul >> 16));
    }
  }
  if (lane < 8) {
    if (RESID) {
      unsigned r = *(const unsigned*)(src + (size_t)t * 256 + 128 + p * 16 + cl * 2);
      a0 += bf2f((unsigned short)r);
      a1 += bf2f((unsigned short)(r >> 16));
      float2 o = {a0, a1};
      *(float2*)(dst_f32 + (size_t)t * 128 + p * 16 + cl * 2) = o;
    } else {
      *(unsigned*)(dst_bf + (size_t)t * 256 + p * 16 + cl * 2) =
          (unsigned)f2bf(a0) | ((unsigned)f2bf(a1) << 16);
    }
  }
}

// ---------------- GEMM ----------------

// Fused pack of both weight matrices into MFMA-B fragment layout.
// id < 65536: Bp1 = vstack(Wl1, Wr1) (256x256); else Bp2 = hstack(Wl2, Wr2).
__global__ void k_packs(const float* __restrict__ Wl1, const float* __restrict__ Wr1,
                        const float* __restrict__ Wl2, const float* __restrict__ Wr2,
                        short* __restrict__ Bp1, short* __restrict__ Bp2) {
  int id = blockIdx.x * 256 + threadIdx.x;
  bool second = id >= 65536;
  int lid = id & 65535;
  int j = lid & 7;
  int lane = (lid >> 3) & 63;
  int blk = lid >> 9;
  int nb = blk & 15;
  int kk = blk >> 4;
  int k = kk * 32 + (lane >> 4) * 8 + j;
  int c = nb * 16 + (lane & 15);
  float v;
  if (!second) v = (k < 128) ? Wl1[k * 256 + c] : Wr1[(k - 128) * 256 + c];
  else         v = (c < 128) ? Wl2[k * 128 + c] : Wr2[k * 128 + (c - 128)];
  (second ? Bp2 : Bp1)[lid] = (short)f2bf(v);
}

// C[M x 256] = A[M x 256](bf16) * Bp (+bias per BIAS_MODE), optional relu.
// 128x128 tile, 4 waves 2x2, each wave 64x64 (4x4 16x16x32 frags).
// Grid dim3(2, 784); XCD-chunked bijective decode so both col-halves of a
// row-tile run consecutively on the SAME XCD -> A-tile L2 reuse.
// BIAS_MODE: 0 = bias[colg]; 1 = colg<128 ? 0 : bias[colg-128]
template <int KK, int NBTOT, bool RELU, bool OUT_BF16, int BIAS_MODE>
__global__ __launch_bounds__(256) void k_gemm(const short* __restrict__ A, int lda,
                                              const short* __restrict__ Bp,
                                              const float* __restrict__ bias,
                                              void* __restrict__ out, int ldc,
                                              int mlimit) {
  const int L = blockIdx.x + 2 * blockIdx.y;
  const int xcd = L & 7;
  const int rnd = L >> 3;          // 0..195
  const int colhalf = rnd & 1;
  const int rt = (rnd >> 1) + 98 * xcd;
  if (rt >= MTILES) return;

  const int lane = threadIdx.x & 63;
  const int wave = threadIdx.x >> 6;
  const int wr = wave >> 1, wc = wave & 1;
  const int row0 = rt * 128 + wr * 64;
  const int colbase = colhalf * 128 + wc * 64;
  const int arow = lane & 15;
  const int kgrp = lane >> 4;

  f32x4 acc[4][4];
  const f32x4 zero = {0.f, 0.f, 0.f, 0.f};
  #pragma unroll
  for (int a = 0; a < 4; ++a)
    #pragma unroll
    for (int b = 0; b < 4; ++b) acc[a][b] = zero;

  const short* Bbase = Bp + (size_t)lane * 8;
  for (int kk = 0; kk < KK; ++kk) {
    short8 af[4], bfr[4];
    const int kb = kk * 32 + kgrp * 8;
    #pragma unroll
    for (int mi = 0; mi < 4; ++mi)
      af[mi] = *(const short8*)(A + (size_t)(row0 + mi * 16 + arow) * lda + kb);
    #pragma unroll
    for (int ni = 0; ni < 4; ++ni) {
      int nb = (colbase >> 4) + ni;
      bfr[ni] = *(const short8*)(Bbase + ((size_t)(kk * NBTOT + nb) << 9));
    }
    #pragma unroll
    for (int mi = 0; mi < 4; ++mi)
      #pragma unroll
      for (int ni = 0; ni < 4; ++ni)
        acc[mi][ni] = __builtin_amdgcn_mfma_f32_16x16x32_bf16(af[mi], bfr[ni],
                                                              acc[mi][ni], 0, 0, 0);
  }

  const int ccol = lane & 15;
  const int crow = (lane >> 4) * 4;
  #pragma unroll
  for (int ni = 0; ni < 4; ++ni) {
    const int colg = colbase + ni * 16 + ccol;
    float bv;
    if (BIAS_MODE == 0) bv = bias[colg];
    else bv = (colg < 128) ? 0.f : bias[colg - 128];
    #pragma unroll
    for (int mi = 0; mi < 4; ++mi) {
      #pragma unroll
      for (int j = 0; j < 4; ++j) {
        int rowg = row0 + mi * 16 + crow + j;
        float v = acc[mi][ni][j] + bv;
        if (RELU) v = fmaxf(v, 0.0f);
        if (OUT_BF16) {
          ((short*)out)[(size_t)rowg * ldc + colg] = (short)f2bf(v);
        } else {
          if (rowg < mlimit)
            ((float*)out)[(size_t)rowg * ldc + colg] = v;
        }
      }
    }
  }
}

extern "C" void kernel_launch(void* const* d_in, const int* in_sizes, int n_in,
                              void* d_out, int out_size, void* d_ws, size_t ws_size,
                              hipStream_t stream) {
  const float* x   = (const float*)d_in[0];
  const int*   row = (const int*)d_in[1];
  const int*   col = (const int*)d_in[2];
  const float* Wl1 = (const float*)d_in[3];
  const float* bl1 = (const float*)d_in[4];
  const float* Wr1 = (const float*)d_in[5];
  const float* Wl2 = (const float*)d_in[6];
  const float* bl2 = (const float*)d_in[7];
  const float* Wr2 = (const float*)d_in[8];
  float* out = (float*)d_out;

  char* w = (char*)d_ws;
  auto alloc = [&](size_t bytes) {
    char* p = w;
    w += (bytes + 255) & ~(size_t)255;
    return p;
  };
  short* Acat = (short*)alloc((size_t)MPAD * 256 * 2);  // [agg_x_bf16 | x_bf16]
  short* Hbuf = (short*)alloc((size_t)MPAD * 256 * 2);  // h (post-relu), bf16
  short* P    = (short*)alloc((size_t)MPAD * 256 * 2);  // [h@Wl2 | h@Wr2+bl2], bf16
  short* Bp1  = (short*)alloc(65536 * 2);               // [Wl1;Wr1] packed (vcat)
  short* Bp2  = (short*)alloc(65536 * 2);               // [Wl2|Wr2] packed (hcat)
  int* rp   = (int*)alloc((N_NODES + 1) * 4);
  int* cs   = (int*)alloc((size_t)N_EDGES * 4);
  unsigned* tmp = (unsigned*)alloc((size_t)N_EDGES * 4);
  int* Hc   = (int*)alloc((size_t)NB * NBLK_A * 4);
  int* G    = (int*)alloc((size_t)NB * NBLK_A * 4);
  int* Boff = (int*)alloc((NB + 1) * 4);

  // --- CSR build: two-level counting sort (no global data atomics) ---
  k_bhist<<<NBLK_A, 256, 0, stream>>>(row, Hc);
  k_bscan<<<1, 512, 0, stream>>>(Hc, Boff);
  k_bexp<<<NB, 64, 0, stream>>>(Hc, Boff, G);
  k_bscat<<<NBLK_A, 256, 0, stream>>>(row, col, G, tmp);
  k_bsort<<<NB, 256, 0, stream>>>(tmp, Boff, rp, cs);

  // --- weight packing + x conversion (independent of CSR) ---
  k_cvt_x<<<(N_NODES * 32 + 255) / 256, 256, 0, stream>>>(x, Acat);
  k_packs<<<512, 256, 0, stream>>>(Wl1, Wr1, Wl2, Wr2, Bp1, Bp2);

  const int AGG_BLOCKS = 8 * ((N_NODES + 3) / 4);   // 8 partitions x node groups

  // --- layer 1: agg(x) ; h = relu([agg|x] @ [Wl1;Wr1] + bl1) -> Hbuf bf16 ---
  k_agg<false, 128><<<AGG_BLOCKS, 256, 0, stream>>>(
      rp, cs, Acat, Acat, nullptr);
  k_gemm<8, 16, true, true, 0><<<dim3(2, 784), 256, 0, stream>>>(
      Acat, 256, Bp1, bl1, Hbuf, 256, MPAD);

  // --- layer 2: P = h @ [Wl2 | Wr2] (+bl2 on right half) ; out = agg(P_l) + P_r ---
  k_gemm<8, 16, false, true, 1><<<dim3(2, 784), 256, 0, stream>>>(
      Hbuf, 256, Bp2, bl2, P, 256, MPAD);
  k_agg<true, 0><<<AGG_BLOCKS, 256, 0, stream>>>(
      rp, cs, P, nullptr, out);
}

// Round 10
// 314.282 us; speedup vs baseline: 2.5179x; 2.5179x over previous
//
#include <hip/hip_runtime.h>

#define N_NODES 100000
#define N_EDGES 1600000
#define MPAD    100096   /* 782 * 128 */
#define MTILES  782

#define NB      391      /* ceil(100000/256) buckets of 256 nodes */
#define CH      4096     /* edges per phase-A block */
#define NBLK_A  391      /* ceil(1600000/4096) */

typedef __attribute__((ext_vector_type(8))) short short8;
typedef __attribute__((ext_vector_type(4))) float f32x4;

static __device__ __forceinline__ unsigned short f2bf(float f) {
  unsigned u = __builtin_bit_cast(unsigned, f);
  u += 0x7fffu + ((u >> 16) & 1u);     // round-to-nearest-even
  return (unsigned short)(u >> 16);
}
static __device__ __forceinline__ float bf2f(unsigned short s) {
  unsigned u = ((unsigned)s) << 16;
  return __builtin_bit_cast(float, u);
}

// ---------------- CSR build: two-level LDS counting sort ----------------

__global__ __launch_bounds__(256) void k_bhist(const int* __restrict__ row,
                                               int* __restrict__ Hc) {
  __shared__ int hist[NB];
  int b = blockIdx.x, t = threadIdx.x;
  for (int j = t; j < NB; j += 256) hist[j] = 0;
  __syncthreads();
  int base = b * CH;
  #pragma unroll
  for (int k = 0; k < 4; ++k) {
    int i = base + k * 1024 + t * 4;
    if (i < N_EDGES) {
      int4 r = *(const int4*)(row + i);
      atomicAdd(&hist[r.x >> 8], 1);
      atomicAdd(&hist[r.y >> 8], 1);
      atomicAdd(&hist[r.z >> 8], 1);
      atomicAdd(&hist[r.w >> 8], 1);
    }
  }
  __syncthreads();
  for (int j = t; j < NB; j += 256) Hc[j * NBLK_A + b] = hist[j];
}

__global__ __launch_bounds__(512) void k_bscan(const int* __restrict__ Hc,
                                               int* __restrict__ Boff) {
  int t = threadIdx.x;
  int total = 0;
  if (t < NB) {
    const int* p = Hc + t * NBLK_A;
    int i = 0;
    for (; i + 4 <= NBLK_A; i += 4) {
      int4 v = *(const int4*)(p + i);
      total += v.x + v.y + v.z + v.w;
    }
    for (; i < NBLK_A; ++i) total += p[i];
  }
  int lane = t & 63, w = t >> 6;
  int incl = total;
  #pragma unroll
  for (int off = 1; off < 64; off <<= 1) {
    int n = __shfl_up(incl, off, 64);
    if (lane >= off) incl += n;
  }
  __shared__ int ws[8];
  if (lane == 63) ws[w] = incl;
  __syncthreads();
  int wo = 0;
  for (int ww = 0; ww < w; ++ww) wo += ws[ww];
  int excl = wo + incl - total;
  if (t < NB) Boff[t] = excl;
  if (t == NB - 1) Boff[NB] = excl + total;
}

__global__ __launch_bounds__(64) void k_bexp(const int* __restrict__ Hc,
                                             const int* __restrict__ Boff,
                                             int* __restrict__ G) {
  int b = blockIdx.x, l = threadIdx.x;
  int run = Boff[b];
  const int* p = Hc + b * NBLK_A;
  for (int c = 0; c < NBLK_A; c += 64) {
    int idx = c + l;
    int v = (idx < NBLK_A) ? p[idx] : 0;
    int incl = v;
    #pragma unroll
    for (int off = 1; off < 64; off <<= 1) {
      int n = __shfl_up(incl, off, 64);
      if (l >= off) incl += n;
    }
    if (idx < NBLK_A) G[b * NBLK_A + idx] = run + incl - v;
    run += __shfl(incl, 63, 64);
  }
}

__global__ __launch_bounds__(256) void k_bscat(const int* __restrict__ row,
                                               const int* __restrict__ col,
                                               const int* __restrict__ G,
                                               unsigned* __restrict__ tmp) {
  __shared__ int cur[NB];
  int b = blockIdx.x, t = threadIdx.x;
  for (int j = t; j < NB; j += 256) cur[j] = G[j * NBLK_A + b];
  __syncthreads();
  int base = b * CH;
  #pragma unroll
  for (int k = 0; k < 4; ++k) {
    int i = base + k * 1024 + t * 4;
    if (i < N_EDGES) {
      int4 r = *(const int4*)(row + i);
      int4 c = *(const int4*)(col + i);
      int p0 = atomicAdd(&cur[r.x >> 8], 1);
      tmp[p0] = (unsigned)c.x | ((unsigned)(r.x & 255) << 24);
      int p1 = atomicAdd(&cur[r.y >> 8], 1);
      tmp[p1] = (unsigned)c.y | ((unsigned)(r.y & 255) << 24);
      int p2 = atomicAdd(&cur[r.z >> 8], 1);
      tmp[p2] = (unsigned)c.z | ((unsigned)(r.z & 255) << 24);
      int p3 = atomicAdd(&cur[r.w >> 8], 1);
      tmp[p3] = (unsigned)c.w | ((unsigned)(r.w & 255) << 24);
    }
  }
}

__global__ __launch_bounds__(256) void k_bsort(const unsigned* __restrict__ tmp,
                                               const int* __restrict__ Boff,
                                               int* __restrict__ rp,
                                               int* __restrict__ cs) {
  __shared__ int hist[256];
  __shared__ int wsum[4];
  int b = blockIdx.x, t = threadIdx.x;
  int s = Boff[b], e = Boff[b + 1];
  hist[t] = 0;
  __syncthreads();
  for (int i = s + t; i < e; i += 256) atomicAdd(&hist[tmp[i] >> 24], 1);
  __syncthreads();
  int v = hist[t];
  int lane = t & 63, w = t >> 6;
  int incl = v;
  #pragma unroll
  for (int off = 1; off < 64; off <<= 1) {
    int n = __shfl_up(incl, off, 64);
    if (lane >= off) incl += n;
  }
  if (lane == 63) wsum[w] = incl;
  __syncthreads();
  int wo = 0;
  for (int ww = 0; ww < w; ++ww) wo += wsum[ww];
  int excl = s + wo + incl - v;
  int node = (b << 8) + t;
  if (node < N_NODES) rp[node] = excl;
  __syncthreads();
  hist[t] = excl;    // reuse as cursor
  __syncthreads();
  for (int i = s + t; i < e; i += 256) {
    unsigned u = tmp[i];
    int pos = atomicAdd(&hist[u >> 24], 1);
    cs[pos] = (int)(u & 0xFFFFFFu);
  }
  if (b == 0 && t == 0) rp[N_NODES] = N_EDGES;
}

// ---------------- prep: weight pack + x f32->bf16 (fused launch) ----------------

// blocks 0..511: pack Bp1 (vstack Wl1,Wr1) and Bp2 (hstack Wl2,Wr2)
// blocks 512.. : cvt x -> bf16 into Acat[:,128:256]
__global__ __launch_bounds__(256) void k_prep(const float* __restrict__ x,
                                              const float* __restrict__ Wl1,
                                              const float* __restrict__ Wr1,
                                              const float* __restrict__ Wl2,
                                              const float* __restrict__ Wr2,
                                              short* __restrict__ Bp1,
                                              short* __restrict__ Bp2,
                                              short* __restrict__ Acat) {
  if (blockIdx.x < 512) {
    int id = blockIdx.x * 256 + threadIdx.x;
    bool second = id >= 65536;
    int lid = id & 65535;
    int j = lid & 7;
    int lane = (lid >> 3) & 63;
    int blk = lid >> 9;
    int nb = blk & 15;
    int kk = blk >> 4;
    int k = kk * 32 + (lane >> 4) * 8 + j;
    int c = nb * 16 + (lane & 15);
    float v;
    if (!second) v = (k < 128) ? Wl1[k * 256 + c] : Wr1[(k - 128) * 256 + c];
    else         v = (c < 128) ? Wl2[k * 128 + c] : Wr2[k * 128 + (c - 128)];
    (second ? Bp2 : Bp1)[lid] = (short)f2bf(v);
  } else {
    int id = (blockIdx.x - 512) * 256 + threadIdx.x;
    if (id >= N_NODES * 32) return;
    int node = id >> 5, c4 = id & 31;
    float4 v = *(const float4*)(x + (size_t)node * 128 + c4 * 4);
    uint2 u;
    u.x = (unsigned)f2bf(v.x) | ((unsigned)f2bf(v.y) << 16);
    u.y = (unsigned)f2bf(v.z) | ((unsigned)f2bf(v.w) << 16);
    *(uint2*)(Acat + (size_t)node * 256 + 128 + c4 * 4) = u;
  }
}

// ---------------- aggregation (R7 version: known 64.5 us) ----------------

// Node-per-wave aggregation, scalarized uniform path + tail-correction.
// Node id readfirstlane'd -> rp/cs loads, indices, gather bases all scalar;
// per-edge VALU = 2 cvt + 2 add. ceil(d/16) rounds of 16 clamped gathers,
// unconditional accumulate, then subtract over*row[last] once (exact).
// Gathered slice = dwords [GOFF, GOFF+64) of each 256-short source row.
// RESID: add src[t,128:256], write f32 to dst_f32; else bf16 to dst_bf.
template <bool RESID, int GOFF>
__global__ __launch_bounds__(256) void k_agg(const int* __restrict__ rp,
                                             const int* __restrict__ cs,
                                             const short* __restrict__ src,
                                             short* __restrict__ dst_bf,
                                             float* __restrict__ dst_f32) {
  const int t = __builtin_amdgcn_readfirstlane(blockIdx.x * 4 + (threadIdx.x >> 6));
  if (t >= N_NODES) return;
  const int lane = threadIdx.x & 63;
  const int s = rp[t], e = rp[t + 1];
  const int d = e - s;
  float a0 = 0.f, a1 = 0.f;
  const short* gb = src + GOFF + 2 * lane;
  if (d > 0) {
    const int last = e - 1;
    const int rounds = (d + 15) >> 4;
    for (int r = 0; r < rounds; ++r) {
      int base = s + (r << 4);
      unsigned u[16];
      #pragma unroll
      for (int q = 0; q < 16; ++q) {
        int j = base + q;
        j = (j < last) ? j : last;                       // wave-uniform clamp
        u[q] = *(const unsigned*)(gb + (size_t)cs[j] * 256);
      }
      #pragma unroll
      for (int q = 0; q < 16; ++q) {
        a0 += bf2f((unsigned short)u[q]);
        a1 += bf2f((unsigned short)(u[q] >> 16));
      }
    }
    const int over = (rounds << 4) - d;
    if (over) {
      unsigned ul = *(const unsigned*)(gb + (size_t)cs[last] * 256);
      float c = (float)over;
      a0 -= c * bf2f((unsigned short)ul);
      a1 -= c * bf2f((unsigned short)(ul >> 16));
    }
  }
  if (RESID) {
    unsigned r = *(const unsigned*)(src + (size_t)t * 256 + 128 + 2 * lane);
    a0 += bf2f((unsigned short)r);
    a1 += bf2f((unsigned short)(r >> 16));
    float2 o = {a0, a1};
    *(float2*)(dst_f32 + (size_t)t * 128 + 2 * lane) = o;
  } else {
    *(unsigned*)(dst_bf + (size_t)t * 256 + 2 * lane) =
        (unsigned)f2bf(a0) | ((unsigned)f2bf(a1) << 16);
  }
}

// ---------------- GEMM ----------------

// C[M x 256] = A[M x 256](bf16) * Bp (+bias per BIAS_MODE), optional relu.
// Full-N tile: 128x256 per block, 512 threads = 8 waves (2 rows x 4 cols of
// 64x64 wave tiles). A-tile read ONCE per block (no col-half refetch).
// BIAS_MODE: 0 = bias[colg]; 1 = colg<128 ? 0 : bias[colg-128]
template <int KK, int NBTOT, bool RELU, bool OUT_BF16, int BIAS_MODE>
__global__ __launch_bounds__(512) void k_gemm(const short* __restrict__ A, int lda,
                                              const short* __restrict__ Bp,
                                              const float* __restrict__ bias,
                                              void* __restrict__ out, int ldc,
                                              int mlimit) {
  const int lane = threadIdx.x & 63;
  const int wave = threadIdx.x >> 6;
  const int wr = wave >> 2, wc = wave & 3;
  const int row0 = blockIdx.x * 128 + wr * 64;
  const int colbase = wc * 64;
  const int arow = lane & 15;
  const int kgrp = lane >> 4;

  f32x4 acc[4][4];
  const f32x4 zero = {0.f, 0.f, 0.f, 0.f};
  #pragma unroll
  for (int a = 0; a < 4; ++a)
    #pragma unroll
    for (int b = 0; b < 4; ++b) acc[a][b] = zero;

  const short* Bbase = Bp + (size_t)lane * 8;
  for (int kk = 0; kk < KK; ++kk) {
    short8 af[4], bfr[4];
    const int kb = kk * 32 + kgrp * 8;
    #pragma unroll
    for (int mi = 0; mi < 4; ++mi)
      af[mi] = *(const short8*)(A + (size_t)(row0 + mi * 16 + arow) * lda + kb);
    #pragma unroll
    for (int ni = 0; ni < 4; ++ni) {
      int nb = (colbase >> 4) + ni;
      bfr[ni] = *(const short8*)(Bbase + ((size_t)(kk * NBTOT + nb) << 9));
    }
    #pragma unroll
    for (int mi = 0; mi < 4; ++mi)
      #pragma unroll
      for (int ni = 0; ni < 4; ++ni)
        acc[mi][ni] = __builtin_amdgcn_mfma_f32_16x16x32_bf16(af[mi], bfr[ni],
                                                              acc[mi][ni], 0, 0, 0);
  }

  const int ccol = lane & 15;
  const int crow = (lane >> 4) * 4;
  #pragma unroll
  for (int ni = 0; ni < 4; ++ni) {
    const int colg = colbase + ni * 16 + ccol;
    float bv;
    if (BIAS_MODE == 0) bv = bias[colg];
    else bv = (colg < 128) ? 0.f : bias[colg - 128];
    #pragma unroll
    for (int mi = 0; mi < 4; ++mi) {
      #pragma unroll
      for (int j = 0; j < 4; ++j) {
        int rowg = row0 + mi * 16 + crow + j;
        float v = acc[mi][ni][j] + bv;
        if (RELU) v = fmaxf(v, 0.0f);
        if (OUT_BF16) {
          ((short*)out)[(size_t)rowg * ldc + colg] = (short)f2bf(v);
        } else {
          if (rowg < mlimit)
            ((float*)out)[(size_t)rowg * ldc + colg] = v;
        }
      }
    }
  }
}

extern "C" void kernel_launch(void* const* d_in, const int* in_sizes, int n_in,
                              void* d_out, int out_size, void* d_ws, size_t ws_size,
                              hipStream_t stream) {
  const float* x   = (const float*)d_in[0];
  const int*   row = (const int*)d_in[1];
  const int*   col = (const int*)d_in[2];
  const float* Wl1 = (const float*)d_in[3];
  const float* bl1 = (const float*)d_in[4];
  const float* Wr1 = (const float*)d_in[5];
  const float* Wl2 = (const float*)d_in[6];
  const float* bl2 = (const float*)d_in[7];
  const float* Wr2 = (const float*)d_in[8];
  float* out = (float*)d_out;

  char* w = (char*)d_ws;
  auto alloc = [&](size_t bytes) {
    char* p = w;
    w += (bytes + 255) & ~(size_t)255;
    return p;
  };
  short* Acat = (short*)alloc((size_t)MPAD * 256 * 2);  // [agg_x_bf16 | x_bf16]
  short* Hbuf = (short*)alloc((size_t)MPAD * 256 * 2);  // h (post-relu), bf16
  short* P    = (short*)alloc((size_t)MPAD * 256 * 2);  // [h@Wl2 | h@Wr2+bl2], bf16
  short* Bp1  = (short*)alloc(65536 * 2);               // [Wl1;Wr1] packed (vcat)
  short* Bp2  = (short*)alloc(65536 * 2);               // [Wl2|Wr2] packed (hcat)
  int* rp   = (int*)alloc((N_NODES + 1) * 4);
  int* cs   = (int*)alloc((size_t)N_EDGES * 4);
  unsigned* tmp = (unsigned*)alloc((size_t)N_EDGES * 4);
  int* Hc   = (int*)alloc((size_t)NB * NBLK_A * 4);
  int* G    = (int*)alloc((size_t)NB * NBLK_A * 4);
  int* Boff = (int*)alloc((NB + 1) * 4);

  // --- CSR build: two-level counting sort (no global data atomics) ---
  k_bhist<<<NBLK_A, 256, 0, stream>>>(row, Hc);
  k_bscan<<<1, 512, 0, stream>>>(Hc, Boff);
  k_bexp<<<NB, 64, 0, stream>>>(Hc, Boff, G);
  k_bscat<<<NBLK_A, 256, 0, stream>>>(row, col, G, tmp);
  k_bsort<<<NB, 256, 0, stream>>>(tmp, Boff, rp, cs);

  // --- fused weight packing + x conversion (independent of CSR) ---
  k_prep<<<512 + (N_NODES * 32 + 255) / 256, 256, 0, stream>>>(
      x, Wl1, Wr1, Wl2, Wr2, Bp1, Bp2, Acat);

  // --- layer 1: agg(x) ; h = relu([agg|x] @ [Wl1;Wr1] + bl1) -> Hbuf bf16 ---
  k_agg<false, 128><<<(N_NODES + 3) / 4, 256, 0, stream>>>(
      rp, cs, Acat, Acat, nullptr);
  k_gemm<8, 16, true, true, 0><<<MTILES, 512, 0, stream>>>(
      Acat, 256, Bp1, bl1, Hbuf, 256, MPAD);

  // --- layer 2: P = h @ [Wl2 | Wr2] (+bl2 on right half) ; out = agg(P_l) + P_r ---
  k_gemm<8, 16, false, true, 1><<<MTILES, 512, 0, stream>>>(
      Hbuf, 256, Bp2, bl2, P, 256, MPAD);
  k_agg<true, 0><<<(N_NODES + 3) / 4, 256, 0, stream>>>(
      rp, cs, P, nullptr, out);
}

// Round 11
// 290.362 us; speedup vs baseline: 2.7254x; 1.0824x over previous
//
#include <hip/hip_runtime.h>

#define N_NODES 100000
#define N_EDGES 1600000
#define MPAD    100096   /* 782 * 128 */
#define MTILES  782

#define NB      391      /* ceil(100000/256) buckets of 256 nodes */
#define CH      4096     /* edges per phase-A block */
#define NBLK_A  391      /* ceil(1600000/4096) */

typedef __attribute__((ext_vector_type(8))) short short8;
typedef __attribute__((ext_vector_type(4))) float f32x4;

static __device__ __forceinline__ unsigned short f2bf(float f) {
  unsigned u = __builtin_bit_cast(unsigned, f);
  u += 0x7fffu + ((u >> 16) & 1u);     // round-to-nearest-even
  return (unsigned short)(u >> 16);
}
static __device__ __forceinline__ float bf2f(unsigned short s) {
  unsigned u = ((unsigned)s) << 16;
  return __builtin_bit_cast(float, u);
}

// ---------------- CSR build: two-level LDS counting sort ----------------

__global__ __launch_bounds__(256) void k_bhist(const int* __restrict__ row,
                                               int* __restrict__ Hc) {
  __shared__ int hist[NB];
  int b = blockIdx.x, t = threadIdx.x;
  for (int j = t; j < NB; j += 256) hist[j] = 0;
  __syncthreads();
  int base = b * CH;
  #pragma unroll
  for (int k = 0; k < 4; ++k) {
    int i = base + k * 1024 + t * 4;
    if (i < N_EDGES) {
      int4 r = *(const int4*)(row + i);
      atomicAdd(&hist[r.x >> 8], 1);
      atomicAdd(&hist[r.y >> 8], 1);
      atomicAdd(&hist[r.z >> 8], 1);
      atomicAdd(&hist[r.w >> 8], 1);
    }
  }
  __syncthreads();
  for (int j = t; j < NB; j += 256) Hc[j * NBLK_A + b] = hist[j];
}

__global__ __launch_bounds__(512) void k_bscan(const int* __restrict__ Hc,
                                               int* __restrict__ Boff) {
  int t = threadIdx.x;
  int total = 0;
  if (t < NB) {
    const int* p = Hc + t * NBLK_A;
    int i = 0;
    for (; i + 4 <= NBLK_A; i += 4) {
      int4 v = *(const int4*)(p + i);
      total += v.x + v.y + v.z + v.w;
    }
    for (; i < NBLK_A; ++i) total += p[i];
  }
  int lane = t & 63, w = t >> 6;
  int incl = total;
  #pragma unroll
  for (int off = 1; off < 64; off <<= 1) {
    int n = __shfl_up(incl, off, 64);
    if (lane >= off) incl += n;
  }
  __shared__ int ws[8];
  if (lane == 63) ws[w] = incl;
  __syncthreads();
  int wo = 0;
  for (int ww = 0; ww < w; ++ww) wo += ws[ww];
  int excl = wo + incl - total;
  if (t < NB) Boff[t] = excl;
  if (t == NB - 1) Boff[NB] = excl + total;
}

__global__ __launch_bounds__(64) void k_bexp(const int* __restrict__ Hc,
                                             const int* __restrict__ Boff,
                                             int* __restrict__ G) {
  int b = blockIdx.x, l = threadIdx.x;
  int run = Boff[b];
  const int* p = Hc + b * NBLK_A;
  for (int c = 0; c < NBLK_A; c += 64) {
    int idx = c + l;
    int v = (idx < NBLK_A) ? p[idx] : 0;
    int incl = v;
    #pragma unroll
    for (int off = 1; off < 64; off <<= 1) {
      int n = __shfl_up(incl, off, 64);
      if (l >= off) incl += n;
    }
    if (idx < NBLK_A) G[b * NBLK_A + idx] = run + incl - v;
    run += __shfl(incl, 63, 64);
  }
}

__global__ __launch_bounds__(256) void k_bscat(const int* __restrict__ row,
                                               const int* __restrict__ col,
                                               const int* __restrict__ G,
                                               unsigned* __restrict__ tmp) {
  __shared__ int cur[NB];
  int b = blockIdx.x, t = threadIdx.x;
  for (int j = t; j < NB; j += 256) cur[j] = G[j * NBLK_A + b];
  __syncthreads();
  int base = b * CH;
  #pragma unroll
  for (int k = 0; k < 4; ++k) {
    int i = base + k * 1024 + t * 4;
    if (i < N_EDGES) {
      int4 r = *(const int4*)(row + i);
      int4 c = *(const int4*)(col + i);
      int p0 = atomicAdd(&cur[r.x >> 8], 1);
      tmp[p0] = (unsigned)c.x | ((unsigned)(r.x & 255) << 24);
      int p1 = atomicAdd(&cur[r.y >> 8], 1);
      tmp[p1] = (unsigned)c.y | ((unsigned)(r.y & 255) << 24);
      int p2 = atomicAdd(&cur[r.z >> 8], 1);
      tmp[p2] = (unsigned)c.z | ((unsigned)(r.z & 255) << 24);
      int p3 = atomicAdd(&cur[r.w >> 8], 1);
      tmp[p3] = (unsigned)c.w | ((unsigned)(r.w & 255) << 24);
    }
  }
}

__global__ __launch_bounds__(256) void k_bsort(const unsigned* __restrict__ tmp,
                                               const int* __restrict__ Boff,
                                               int* __restrict__ rp,
                                               int* __restrict__ cs) {
  __shared__ int hist[256];
  __shared__ int wsum[4];
  int b = blockIdx.x, t = threadIdx.x;
  int s = Boff[b], e = Boff[b + 1];
  hist[t] = 0;
  __syncthreads();
  for (int i = s + t; i < e; i += 256) atomicAdd(&hist[tmp[i] >> 24], 1);
  __syncthreads();
  int v = hist[t];
  int lane = t & 63, w = t >> 6;
  int incl = v;
  #pragma unroll
  for (int off = 1; off < 64; off <<= 1) {
    int n = __shfl_up(incl, off, 64);
    if (lane >= off) incl += n;
  }
  if (lane == 63) wsum[w] = incl;
  __syncthreads();
  int wo = 0;
  for (int ww = 0; ww < w; ++ww) wo += wsum[ww];
  int excl = s + wo + incl - v;
  int node = (b << 8) + t;
  if (node < N_NODES) rp[node] = excl;
  __syncthreads();
  hist[t] = excl;    // reuse as cursor
  __syncthreads();
  for (int i = s + t; i < e; i += 256) {
    unsigned u = tmp[i];
    int pos = atomicAdd(&hist[u >> 24], 1);
    cs[pos] = (int)(u & 0xFFFFFFu);
  }
  if (b == 0 && t == 0) rp[N_NODES] = N_EDGES;
}

// ---------------- prep: weight pack + x f32->bf16 (fused launch) ----------------

// blocks 0..511: pack Bp1 (vstack Wl1,Wr1) and Bp2 (hstack Wl2,Wr2)
// blocks 512.. : cvt x -> bf16 into Acat[:,128:256]
__global__ __launch_bounds__(256) void k_prep(const float* __restrict__ x,
                                              const float* __restrict__ Wl1,
                                              const float* __restrict__ Wr1,
                                              const float* __restrict__ Wl2,
                                              const float* __restrict__ Wr2,
                                              short* __restrict__ Bp1,
                                              short* __restrict__ Bp2,
                                              short* __restrict__ Acat) {
  if (blockIdx.x < 512) {
    int id = blockIdx.x * 256 + threadIdx.x;
    bool second = id >= 65536;
    int lid = id & 65535;
    int j = lid & 7;
    int lane = (lid >> 3) & 63;
    int blk = lid >> 9;
    int nb = blk & 15;
    int kk = blk >> 4;
    int k = kk * 32 + (lane >> 4) * 8 + j;
    int c = nb * 16 + (lane & 15);
    float v;
    if (!second) v = (k < 128) ? Wl1[k * 256 + c] : Wr1[(k - 128) * 256 + c];
    else         v = (c < 128) ? Wl2[k * 128 + c] : Wr2[k * 128 + (c - 128)];
    (second ? Bp2 : Bp1)[lid] = (short)f2bf(v);
  } else {
    int id = (blockIdx.x - 512) * 256 + threadIdx.x;
    if (id >= N_NODES * 32) return;
    int node = id >> 5, c4 = id & 31;
    float4 v = *(const float4*)(x + (size_t)node * 128 + c4 * 4);
    uint2 u;
    u.x = (unsigned)f2bf(v.x) | ((unsigned)f2bf(v.y) << 16);
    u.y = (unsigned)f2bf(v.z) | ((unsigned)f2bf(v.w) << 16);
    *(uint2*)(Acat + (size_t)node * 256 + 128 + c4 * 4) = u;
  }
}

// ---------------- aggregation (R7 version: measured 64.4 us) ----------------

// Node-per-wave aggregation, scalarized uniform path + tail-correction.
// Node id readfirstlane'd -> rp/cs loads, indices, gather bases all scalar;
// per-edge VALU = 2 cvt + 2 add. ceil(d/16) rounds of 16 clamped gathers,
// unconditional accumulate, then subtract over*row[last] once (exact).
// Gathered slice = dwords [GOFF, GOFF+64) of each 256-short source row.
// RESID: add src[t,128:256], write f32 to dst_f32; else bf16 to dst_bf.
template <bool RESID, int GOFF>
__global__ __launch_bounds__(256) void k_agg(const int* __restrict__ rp,
                                             const int* __restrict__ cs,
                                             const short* __restrict__ src,
                                             short* __restrict__ dst_bf,
                                             float* __restrict__ dst_f32) {
  const int t = __builtin_amdgcn_readfirstlane(blockIdx.x * 4 + (threadIdx.x >> 6));
  if (t >= N_NODES) return;
  const int lane = threadIdx.x & 63;
  const int s = rp[t], e = rp[t + 1];
  const int d = e - s;
  float a0 = 0.f, a1 = 0.f;
  const short* gb = src + GOFF + 2 * lane;
  if (d > 0) {
    const int last = e - 1;
    const int rounds = (d + 15) >> 4;
    for (int r = 0; r < rounds; ++r) {
      int base = s + (r << 4);
      unsigned u[16];
      #pragma unroll
      for (int q = 0; q < 16; ++q) {
        int j = base + q;
        j = (j < last) ? j : last;                       // wave-uniform clamp
        u[q] = *(const unsigned*)(gb + (size_t)cs[j] * 256);
      }
      #pragma unroll
      for (int q = 0; q < 16; ++q) {
        a0 += bf2f((unsigned short)u[q]);
        a1 += bf2f((unsigned short)(u[q] >> 16));
      }
    }
    const int over = (rounds << 4) - d;
    if (over) {
      unsigned ul = *(const unsigned*)(gb + (size_t)cs[last] * 256);
      float c = (float)over;
      a0 -= c * bf2f((unsigned short)ul);
      a1 -= c * bf2f((unsigned short)(ul >> 16));
    }
  }
  if (RESID) {
    unsigned r = *(const unsigned*)(src + (size_t)t * 256 + 128 + 2 * lane);
    a0 += bf2f((unsigned short)r);
    a1 += bf2f((unsigned short)(r >> 16));
    float2 o = {a0, a1};
    *(float2*)(dst_f32 + (size_t)t * 128 + 2 * lane) = o;
  } else {
    *(unsigned*)(dst_bf + (size_t)t * 256 + 2 * lane) =
        (unsigned)f2bf(a0) | ((unsigned)f2bf(a1) << 16);
  }
}

// ---------------- GEMM (R7 version: measured-good) ----------------

// C[M x 256] = A[M x 256](bf16) * Bp (+bias per BIAS_MODE), optional relu.
// 128x128 tile, 4 waves 2x2, each wave 64x64 (4x4 16x16x32 frags).
// Grid dim3(2, 784); XCD-chunked bijective decode so both col-halves of a
// row-tile run consecutively on the SAME XCD -> A-tile L2 reuse.
// BIAS_MODE: 0 = bias[colg]; 1 = colg<128 ? 0 : bias[colg-128]
template <int KK, int NBTOT, bool RELU, bool OUT_BF16, int BIAS_MODE>
__global__ __launch_bounds__(256) void k_gemm(const short* __restrict__ A, int lda,
                                              const short* __restrict__ Bp,
                                              const float* __restrict__ bias,
                                              void* __restrict__ out, int ldc,
                                              int mlimit) {
  const int L = blockIdx.x + 2 * blockIdx.y;
  const int xcd = L & 7;
  const int rnd = L >> 3;          // 0..195
  const int colhalf = rnd & 1;
  const int rt = (rnd >> 1) + 98 * xcd;
  if (rt >= MTILES) return;

  const int lane = threadIdx.x & 63;
  const int wave = threadIdx.x >> 6;
  const int wr = wave >> 1, wc = wave & 1;
  const int row0 = rt * 128 + wr * 64;
  const int colbase = colhalf * 128 + wc * 64;
  const int arow = lane & 15;
  const int kgrp = lane >> 4;

  f32x4 acc[4][4];
  const f32x4 zero = {0.f, 0.f, 0.f, 0.f};
  #pragma unroll
  for (int a = 0; a < 4; ++a)
    #pragma unroll
    for (int b = 0; b < 4; ++b) acc[a][b] = zero;

  const short* Bbase = Bp + (size_t)lane * 8;
  for (int kk = 0; kk < KK; ++kk) {
    short8 af[4], bfr[4];
    const int kb = kk * 32 + kgrp * 8;
    #pragma unroll
    for (int mi = 0; mi < 4; ++mi)
      af[mi] = *(const short8*)(A + (size_t)(row0 + mi * 16 + arow) * lda + kb);
    #pragma unroll
    for (int ni = 0; ni < 4; ++ni) {
      int nb = (colbase >> 4) + ni;
      bfr[ni] = *(const short8*)(Bbase + ((size_t)(kk * NBTOT + nb) << 9));
    }
    #pragma unroll
    for (int mi = 0; mi < 4; ++mi)
      #pragma unroll
      for (int ni = 0; ni < 4; ++ni)
        acc[mi][ni] = __builtin_amdgcn_mfma_f32_16x16x32_bf16(af[mi], bfr[ni],
                                                              acc[mi][ni], 0, 0, 0);
  }

  const int ccol = lane & 15;
  const int crow = (lane >> 4) * 4;
  #pragma unroll
  for (int ni = 0; ni < 4; ++ni) {
    const int colg = colbase + ni * 16 + ccol;
    float bv;
    if (BIAS_MODE == 0) bv = bias[colg];
    else bv = (colg < 128) ? 0.f : bias[colg - 128];
    #pragma unroll
    for (int mi = 0; mi < 4; ++mi) {
      #pragma unroll
      for (int j = 0; j < 4; ++j) {
        int rowg = row0 + mi * 16 + crow + j;
        float v = acc[mi][ni][j] + bv;
        if (RELU) v = fmaxf(v, 0.0f);
        if (OUT_BF16) {
          ((short*)out)[(size_t)rowg * ldc + colg] = (short)f2bf(v);
        } else {
          if (rowg < mlimit)
            ((float*)out)[(size_t)rowg * ldc + colg] = v;
        }
      }
    }
  }
}

extern "C" void kernel_launch(void* const* d_in, const int* in_sizes, int n_in,
                              void* d_out, int out_size, void* d_ws, size_t ws_size,
                              hipStream_t stream) {
  const float* x   = (const float*)d_in[0];
  const int*   row = (const int*)d_in[1];
  const int*   col = (const int*)d_in[2];
  const float* Wl1 = (const float*)d_in[3];
  const float* bl1 = (const float*)d_in[4];
  const float* Wr1 = (const float*)d_in[5];
  const float* Wl2 = (const float*)d_in[6];
  const float* bl2 = (const float*)d_in[7];
  const float* Wr2 = (const float*)d_in[8];
  float* out = (float*)d_out;

  char* w = (char*)d_ws;
  auto alloc = [&](size_t bytes) {
    char* p = w;
    w += (bytes + 255) & ~(size_t)255;
    return p;
  };
  short* Acat = (short*)alloc((size_t)MPAD * 256 * 2);  // [agg_x_bf16 | x_bf16]
  short* Hbuf = (short*)alloc((size_t)MPAD * 256 * 2);  // h (post-relu), bf16
  short* P    = (short*)alloc((size_t)MPAD * 256 * 2);  // [h@Wl2 | h@Wr2+bl2], bf16
  short* Bp1  = (short*)alloc(65536 * 2);               // [Wl1;Wr1] packed (vcat)
  short* Bp2  = (short*)alloc(65536 * 2);               // [Wl2|Wr2] packed (hcat)
  int* rp   = (int*)alloc((N_NODES + 1) * 4);
  int* cs   = (int*)alloc((size_t)N_EDGES * 4);
  unsigned* tmp = (unsigned*)alloc((size_t)N_EDGES * 4);
  int* Hc   = (int*)alloc((size_t)NB * NBLK_A * 4);
  int* G    = (int*)alloc((size_t)NB * NBLK_A * 4);
  int* Boff = (int*)alloc((NB + 1) * 4);

  // --- CSR build: two-level counting sort (no global data atomics) ---
  k_bhist<<<NBLK_A, 256, 0, stream>>>(row, Hc);
  k_bscan<<<1, 512, 0, stream>>>(Hc, Boff);
  k_bexp<<<NB, 64, 0, stream>>>(Hc, Boff, G);
  k_bscat<<<NBLK_A, 256, 0, stream>>>(row, col, G, tmp);
  k_bsort<<<NB, 256, 0, stream>>>(tmp, Boff, rp, cs);

  // --- fused weight packing + x conversion (independent of CSR) ---
  k_prep<<<512 + (N_NODES * 32 + 255) / 256, 256, 0, stream>>>(
      x, Wl1, Wr1, Wl2, Wr2, Bp1, Bp2, Acat);

  // --- layer 1: agg(x) ; h = relu([agg|x] @ [Wl1;Wr1] + bl1) -> Hbuf bf16 ---
  k_agg<false, 128><<<(N_NODES + 3) / 4, 256, 0, stream>>>(
      rp, cs, Acat, Acat, nullptr);
  k_gemm<8, 16, true, true, 0><<<dim3(2, 784), 256, 0, stream>>>(
      Acat, 256, Bp1, bl1, Hbuf, 256, MPAD);

  // --- layer 2: P = h @ [Wl2 | Wr2] (+bl2 on right half) ; out = agg(P_l) + P_r ---
  k_gemm<8, 16, false, true, 1><<<dim3(2, 784), 256, 0, stream>>>(
      Hbuf, 256, Bp2, bl2, P, 256, MPAD);
  k_agg<true, 0><<<(N_NODES + 3) / 4, 256, 0, stream>>>(
      rp, cs, P, nullptr, out);
}

// Round 12
// 270.360 us; speedup vs baseline: 2.9270x; 1.0740x over previous
//
#include <hip/hip_runtime.h>

#define N_NODES 100000
#define N_EDGES 1600000
#define MPAD    100096   /* 782 * 128 */
#define MTILES  782

#define NB      391      /* ceil(100000/256) buckets of 256 nodes */
#define CH      8192     /* edges per phase-A block */
#define NBLK_A  196      /* ceil(1600000/8192) */

typedef __attribute__((ext_vector_type(8))) short short8;
typedef __attribute__((ext_vector_type(4))) float f32x4;

static __device__ __forceinline__ unsigned short f2bf(float f) {
  unsigned u = __builtin_bit_cast(unsigned, f);
  u += 0x7fffu + ((u >> 16) & 1u);     // round-to-nearest-even
  return (unsigned short)(u >> 16);
}
static __device__ __forceinline__ float bf2f(unsigned short s) {
  unsigned u = ((unsigned)s) << 16;
  return __builtin_bit_cast(float, u);
}

// ---------------- CSR build: two-level LDS counting sort ----------------

__global__ __launch_bounds__(256) void k_bhist(const int* __restrict__ row,
                                               int* __restrict__ Hc) {
  __shared__ int hist[NB];
  int b = blockIdx.x, t = threadIdx.x;
  for (int j = t; j < NB; j += 256) hist[j] = 0;
  __syncthreads();
  int base = b * CH;
  #pragma unroll
  for (int k = 0; k < 8; ++k) {
    int i = base + k * 1024 + t * 4;
    if (i < N_EDGES) {
      int4 r = *(const int4*)(row + i);
      atomicAdd(&hist[r.x >> 8], 1);
      atomicAdd(&hist[r.y >> 8], 1);
      atomicAdd(&hist[r.z >> 8], 1);
      atomicAdd(&hist[r.w >> 8], 1);
    }
  }
  __syncthreads();
  for (int j = t; j < NB; j += 256) Hc[j * NBLK_A + b] = hist[j];
}

__global__ __launch_bounds__(512) void k_bscan(const int* __restrict__ Hc,
                                               int* __restrict__ Boff) {
  int t = threadIdx.x;
  int total = 0;
  if (t < NB) {
    const int* p = Hc + t * NBLK_A;
    for (int i = 0; i < NBLK_A; i += 4) {
      int4 v = *(const int4*)(p + i);
      total += v.x + v.y + v.z + v.w;
    }
  }
  int lane = t & 63, w = t >> 6;
  int incl = total;
  #pragma unroll
  for (int off = 1; off < 64; off <<= 1) {
    int n = __shfl_up(incl, off, 64);
    if (lane >= off) incl += n;
  }
  __shared__ int ws[8];
  if (lane == 63) ws[w] = incl;
  __syncthreads();
  int wo = 0;
  for (int ww = 0; ww < w; ++ww) wo += ws[ww];
  int excl = wo + incl - total;
  if (t < NB) Boff[t] = excl;
  if (t == NB - 1) Boff[NB] = excl + total;
}

__global__ __launch_bounds__(64) void k_bexp(const int* __restrict__ Hc,
                                             const int* __restrict__ Boff,
                                             int* __restrict__ G) {
  int b = blockIdx.x, l = threadIdx.x;
  int run = Boff[b];
  const int* p = Hc + b * NBLK_A;
  for (int c = 0; c < NBLK_A; c += 64) {
    int idx = c + l;
    int v = (idx < NBLK_A) ? p[idx] : 0;
    int incl = v;
    #pragma unroll
    for (int off = 1; off < 64; off <<= 1) {
      int n = __shfl_up(incl, off, 64);
      if (l >= off) incl += n;
    }
    if (idx < NBLK_A) G[b * NBLK_A + idx] = run + incl - v;
    run += __shfl(incl, 63, 64);
  }
}

__global__ __launch_bounds__(256) void k_bscat(const int* __restrict__ row,
                                               const int* __restrict__ col,
                                               const int* __restrict__ G,
                                               unsigned* __restrict__ tmp) {
  __shared__ int cur[NB];
  int b = blockIdx.x, t = threadIdx.x;
  for (int j = t; j < NB; j += 256) cur[j] = G[j * NBLK_A + b];
  __syncthreads();
  int base = b * CH;
  #pragma unroll
  for (int k = 0; k < 8; ++k) {
    int i = base + k * 1024 + t * 4;
    if (i < N_EDGES) {
      int4 r = *(const int4*)(row + i);
      int4 c = *(const int4*)(col + i);
      int p0 = atomicAdd(&cur[r.x >> 8], 1);
      tmp[p0] = (unsigned)c.x | ((unsigned)(r.x & 255) << 24);
      int p1 = atomicAdd(&cur[r.y >> 8], 1);
      tmp[p1] = (unsigned)c.y | ((unsigned)(r.y & 255) << 24);
      int p2 = atomicAdd(&cur[r.z >> 8], 1);
      tmp[p2] = (unsigned)c.z | ((unsigned)(r.z & 255) << 24);
      int p3 = atomicAdd(&cur[r.w >> 8], 1);
      tmp[p3] = (unsigned)c.w | ((unsigned)(r.w & 255) << 24);
    }
  }
}

__global__ __launch_bounds__(256) void k_bsort(const unsigned* __restrict__ tmp,
                                               const int* __restrict__ Boff,
                                               int* __restrict__ rp,
                                               int* __restrict__ cs) {
  __shared__ int hist[256];
  __shared__ int wsum[4];
  int b = blockIdx.x, t = threadIdx.x;
  int s = Boff[b], e = Boff[b + 1];
  hist[t] = 0;
  __syncthreads();
  for (int i = s + t; i < e; i += 256) atomicAdd(&hist[tmp[i] >> 24], 1);
  __syncthreads();
  int v = hist[t];
  int lane = t & 63, w = t >> 6;
  int incl = v;
  #pragma unroll
  for (int off = 1; off < 64; off <<= 1) {
    int n = __shfl_up(incl, off, 64);
    if (lane >= off) incl += n;
  }
  if (lane == 63) wsum[w] = incl;
  __syncthreads();
  int wo = 0;
  for (int ww = 0; ww < w; ++ww) wo += wsum[ww];
  int excl = s + wo + incl - v;
  int node = (b << 8) + t;
  if (node < N_NODES) rp[node] = excl;
  __syncthreads();
  hist[t] = excl;    // reuse as cursor
  __syncthreads();
  for (int i = s + t; i < e; i += 256) {
    unsigned u = tmp[i];
    int pos = atomicAdd(&hist[u >> 24], 1);
    cs[pos] = (int)(u & 0xFFFFFFu);
  }
  if (b == 0 && t == 0) rp[N_NODES] = N_EDGES;
}

// ---------------- prep: weight pack + x f32->bf16 (fused launch) ----------------

__global__ __launch_bounds__(256) void k_prep(const float* __restrict__ x,
                                              const float* __restrict__ Wl1,
                                              const float* __restrict__ Wr1,
                                              const float* __restrict__ Wl2,
                                              const float* __restrict__ Wr2,
                                              short* __restrict__ Bp1,
                                              short* __restrict__ Bp2,
                                              short* __restrict__ Acat) {
  if (blockIdx.x < 512) {
    int id = blockIdx.x * 256 + threadIdx.x;
    bool second = id >= 65536;
    int lid = id & 65535;
    int j = lid & 7;
    int lane = (lid >> 3) & 63;
    int blk = lid >> 9;
    int nb = blk & 15;
    int kk = blk >> 4;
    int k = kk * 32 + (lane >> 4) * 8 + j;
    int c = nb * 16 + (lane & 15);
    float v;
    if (!second) v = (k < 128) ? Wl1[k * 256 + c] : Wr1[(k - 128) * 256 + c];
    else         v = (c < 128) ? Wl2[k * 128 + c] : Wr2[k * 128 + (c - 128)];
    (second ? Bp2 : Bp1)[lid] = (short)f2bf(v);
  } else {
    int id = (blockIdx.x - 512) * 256 + threadIdx.x;
    if (id >= N_NODES * 32) return;
    int node = id >> 5, c4 = id & 31;
    float4 v = *(const float4*)(x + (size_t)node * 128 + c4 * 4);
    uint2 u;
    u.x = (unsigned)f2bf(v.x) | ((unsigned)f2bf(v.y) << 16);
    u.y = (unsigned)f2bf(v.z) | ((unsigned)f2bf(v.w) << 16);
    *(uint2*)(Acat + (size_t)node * 256 + 128 + c4 * 4) = u;
  }
}

// ---------------- aggregation (R7 version: measured 64.4 us) ----------------

template <bool RESID, int GOFF>
__global__ __launch_bounds__(256) void k_agg(const int* __restrict__ rp,
                                             const int* __restrict__ cs,
                                             const short* __restrict__ src,
                                             short* __restrict__ dst_bf,
                                             float* __restrict__ dst_f32) {
  const int t = __builtin_amdgcn_readfirstlane(blockIdx.x * 4 + (threadIdx.x >> 6));
  if (t >= N_NODES) return;
  const int lane = threadIdx.x & 63;
  const int s = rp[t], e = rp[t + 1];
  const int d = e - s;
  float a0 = 0.f, a1 = 0.f;
  const short* gb = src + GOFF + 2 * lane;
  if (d > 0) {
    const int last = e - 1;
    const int rounds = (d + 15) >> 4;
    for (int r = 0; r < rounds; ++r) {
      int base = s + (r << 4);
      unsigned u[16];
      #pragma unroll
      for (int q = 0; q < 16; ++q) {
        int j = base + q;
        j = (j < last) ? j : last;                       // wave-uniform clamp
        u[q] = *(const unsigned*)(gb + (size_t)cs[j] * 256);
      }
      #pragma unroll
      for (int q = 0; q < 16; ++q) {
        a0 += bf2f((unsigned short)u[q]);
        a1 += bf2f((unsigned short)(u[q] >> 16));
      }
    }
    const int over = (rounds << 4) - d;
    if (over) {
      unsigned ul = *(const unsigned*)(gb + (size_t)cs[last] * 256);
      float c = (float)over;
      a0 -= c * bf2f((unsigned short)ul);
      a1 -= c * bf2f((unsigned short)(ul >> 16));
    }
  }
  if (RESID) {
    unsigned r = *(const unsigned*)(src + (size_t)t * 256 + 128 + 2 * lane);
    a0 += bf2f((unsigned short)r);
    a1 += bf2f((unsigned short)(r >> 16));
    float2 o = {a0, a1};
    *(float2*)(dst_f32 + (size_t)t * 128 + 2 * lane) = o;
  } else {
    *(unsigned*)(dst_bf + (size_t)t * 256 + 2 * lane) =
        (unsigned)f2bf(a0) | ((unsigned)f2bf(a1) << 16);
  }
}

// ---------------- GEMM ----------------

// C[M x 256] = A[M x 256](bf16) * Bp (+bias per BIAS_MODE), optional relu.
// 128x128 tile, 4 waves 2x2, each wave 64x64 (4x4 16x16x32 frags).
// Grid dim3(2, 784); XCD-chunked bijective decode so both col-halves of a
// row-tile run consecutively on the SAME XCD -> A-tile L2 reuse.
// Epilogue: bf16 C-tile staged in LDS ([128][136] shorts, 2-way-conflict
// free), then cooperative full-line stores (16 lanes = one 256 B row).
// BIAS_MODE: 0 = bias[colg]; 1 = colg<128 ? 0 : bias[colg-128]
template <int KK, int NBTOT, bool RELU, int BIAS_MODE>
__global__ __launch_bounds__(256) void k_gemm(const short* __restrict__ A, int lda,
                                              const short* __restrict__ Bp,
                                              const float* __restrict__ bias,
                                              short* __restrict__ out, int ldc) {
  __shared__ short cbuf[128][136];
  const int L = blockIdx.x + 2 * blockIdx.y;
  const int xcd = L & 7;
  const int rnd = L >> 3;          // 0..195
  const int colhalf = rnd & 1;
  const int rt = (rnd >> 1) + 98 * xcd;
  if (rt >= MTILES) return;

  const int lane = threadIdx.x & 63;
  const int wave = threadIdx.x >> 6;
  const int wr = wave >> 1, wc = wave & 1;
  const int row0 = rt * 128 + wr * 64;
  const int colbase = colhalf * 128 + wc * 64;
  const int arow = lane & 15;
  const int kgrp = lane >> 4;

  f32x4 acc[4][4];
  const f32x4 zero = {0.f, 0.f, 0.f, 0.f};
  #pragma unroll
  for (int a = 0; a < 4; ++a)
    #pragma unroll
    for (int b = 0; b < 4; ++b) acc[a][b] = zero;

  const short* Bbase = Bp + (size_t)lane * 8;
  for (int kk = 0; kk < KK; ++kk) {
    short8 af[4], bfr[4];
    const int kb = kk * 32 + kgrp * 8;
    #pragma unroll
    for (int mi = 0; mi < 4; ++mi)
      af[mi] = *(const short8*)(A + (size_t)(row0 + mi * 16 + arow) * lda + kb);
    #pragma unroll
    for (int ni = 0; ni < 4; ++ni) {
      int nb = (colbase >> 4) + ni;
      bfr[ni] = *(const short8*)(Bbase + ((size_t)(kk * NBTOT + nb) << 9));
    }
    #pragma unroll
    for (int mi = 0; mi < 4; ++mi)
      #pragma unroll
      for (int ni = 0; ni < 4; ++ni)
        acc[mi][ni] = __builtin_amdgcn_mfma_f32_16x16x32_bf16(af[mi], bfr[ni],
                                                              acc[mi][ni], 0, 0, 0);
  }

  const int ccol = lane & 15;
  const int crow = (lane >> 4) * 4;
  #pragma unroll
  for (int ni = 0; ni < 4; ++ni) {
    const int colg = colbase + ni * 16 + ccol;
    float bv;
    if (BIAS_MODE == 0) bv = bias[colg];
    else bv = (colg < 128) ? 0.f : bias[colg - 128];
    #pragma unroll
    for (int mi = 0; mi < 4; ++mi) {
      #pragma unroll
      for (int j = 0; j < 4; ++j) {
        float v = acc[mi][ni][j] + bv;
        if (RELU) v = fmaxf(v, 0.0f);
        cbuf[wr * 64 + mi * 16 + crow + j][wc * 64 + ni * 16 + ccol] = (short)f2bf(v);
      }
    }
  }
  __syncthreads();

  // cooperative full-line store: 16 lanes = one 256 B row
  const int grp = threadIdx.x & 15;
  const int rbase = threadIdx.x >> 4;      // 0..15
  #pragma unroll
  for (int pp = 0; pp < 8; ++pp) {
    int r = pp * 16 + rbase;
    uint4 v4 = *(const uint4*)&cbuf[r][grp * 8];
    *(uint4*)(out + (size_t)(rt * 128 + r) * ldc + colhalf * 128 + grp * 8) = v4;
  }
}

extern "C" void kernel_launch(void* const* d_in, const int* in_sizes, int n_in,
                              void* d_out, int out_size, void* d_ws, size_t ws_size,
                              hipStream_t stream) {
  const float* x   = (const float*)d_in[0];
  const int*   row = (const int*)d_in[1];
  const int*   col = (const int*)d_in[2];
  const float* Wl1 = (const float*)d_in[3];
  const float* bl1 = (const float*)d_in[4];
  const float* Wr1 = (const float*)d_in[5];
  const float* Wl2 = (const float*)d_in[6];
  const float* bl2 = (const float*)d_in[7];
  const float* Wr2 = (const float*)d_in[8];
  float* out = (float*)d_out;

  char* w = (char*)d_ws;
  auto alloc = [&](size_t bytes) {
    char* p = w;
    w += (bytes + 255) & ~(size_t)255;
    return p;
  };
  short* Acat = (short*)alloc((size_t)MPAD * 256 * 2);  // [agg_x_bf16 | x_bf16]
  short* Hbuf = (short*)alloc((size_t)MPAD * 256 * 2);  // h (post-relu), bf16
  short* P    = (short*)alloc((size_t)MPAD * 256 * 2);  // [h@Wl2 | h@Wr2+bl2], bf16
  short* Bp1  = (short*)alloc(65536 * 2);               // [Wl1;Wr1] packed (vcat)
  short* Bp2  = (short*)alloc(65536 * 2);               // [Wl2|Wr2] packed (hcat)
  int* rp   = (int*)alloc((N_NODES + 1) * 4);
  int* cs   = (int*)alloc((size_t)N_EDGES * 4);
  unsigned* tmp = (unsigned*)alloc((size_t)N_EDGES * 4);
  int* Hc   = (int*)alloc((size_t)NB * NBLK_A * 4);
  int* G    = (int*)alloc((size_t)NB * NBLK_A * 4);
  int* Boff = (int*)alloc((NB + 1) * 4);

  // --- CSR build: two-level counting sort (no global data atomics) ---
  k_bhist<<<NBLK_A, 256, 0, stream>>>(row, Hc);
  k_bscan<<<1, 512, 0, stream>>>(Hc, Boff);
  k_bexp<<<NB, 64, 0, stream>>>(Hc, Boff, G);
  k_bscat<<<NBLK_A, 256, 0, stream>>>(row, col, G, tmp);
  k_bsort<<<NB, 256, 0, stream>>>(tmp, Boff, rp, cs);

  // --- fused weight packing + x conversion (independent of CSR) ---
  k_prep<<<512 + (N_NODES * 32 + 255) / 256, 256, 0, stream>>>(
      x, Wl1, Wr1, Wl2, Wr2, Bp1, Bp2, Acat);

  // --- layer 1: agg(x) ; h = relu([agg|x] @ [Wl1;Wr1] + bl1) -> Hbuf bf16 ---
  k_agg<false, 128><<<(N_NODES + 3) / 4, 256, 0, stream>>>(
      rp, cs, Acat, Acat, nullptr);
  k_gemm<8, 16, true, 0><<<dim3(2, 784), 256, 0, stream>>>(
      Acat, 256, Bp1, bl1, Hbuf, 256);

  // --- layer 2: P = h @ [Wl2 | Wr2] (+bl2 on right half) ; out = agg(P_l) + P_r ---
  k_gemm<8, 16, false, 1><<<dim3(2, 784), 256, 0, stream>>>(
      Hbuf, 256, Bp2, bl2, P, 256);
  k_agg<true, 0><<<(N_NODES + 3) / 4, 256, 0, stream>>>(
      rp, cs, P, nullptr, out);
}

// Round 13
// 251.520 us; speedup vs baseline: 3.1462x; 1.0749x over previous
//
#include <hip/hip_runtime.h>

#define N_NODES 100000
#define N_EDGES 1600000
#define MPAD    100096   /* 782 * 128 */
#define MTILES  782

#define NB      391      /* ceil(100000/256) buckets of 256 nodes */
#define CH      8192     /* edges per phase-A block */
#define NBLK_A  196      /* ceil(1600000/8192) */

typedef __attribute__((ext_vector_type(8))) short short8;
typedef __attribute__((ext_vector_type(4))) float f32x4;

static __device__ __forceinline__ unsigned short f2bf(float f) {
  unsigned u = __builtin_bit_cast(unsigned, f);
  u += 0x7fffu + ((u >> 16) & 1u);     // round-to-nearest-even
  return (unsigned short)(u >> 16);
}
static __device__ __forceinline__ float bf2f(unsigned short s) {
  unsigned u = ((unsigned)s) << 16;
  return __builtin_bit_cast(float, u);
}

// ---------------- CSR build: two-level LDS counting sort ----------------

__global__ __launch_bounds__(256) void k_bhist(const int* __restrict__ row,
                                               int* __restrict__ Hc) {
  __shared__ int hist[NB];
  int b = blockIdx.x, t = threadIdx.x;
  for (int j = t; j < NB; j += 256) hist[j] = 0;
  __syncthreads();
  int base = b * CH;
  #pragma unroll
  for (int k = 0; k < 8; ++k) {
    int i = base + k * 1024 + t * 4;
    if (i < N_EDGES) {
      int4 r = *(const int4*)(row + i);
      atomicAdd(&hist[r.x >> 8], 1);
      atomicAdd(&hist[r.y >> 8], 1);
      atomicAdd(&hist[r.z >> 8], 1);
      atomicAdd(&hist[r.w >> 8], 1);
    }
  }
  __syncthreads();
  for (int j = t; j < NB; j += 256) Hc[j * NBLK_A + b] = hist[j];
}

__global__ __launch_bounds__(512) void k_bscan(const int* __restrict__ Hc,
                                               int* __restrict__ Boff) {
  int t = threadIdx.x;
  int total = 0;
  if (t < NB) {
    const int* p = Hc + t * NBLK_A;
    for (int i = 0; i < NBLK_A; i += 4) {
      int4 v = *(const int4*)(p + i);
      total += v.x + v.y + v.z + v.w;
    }
  }
  int lane = t & 63, w = t >> 6;
  int incl = total;
  #pragma unroll
  for (int off = 1; off < 64; off <<= 1) {
    int n = __shfl_up(incl, off, 64);
    if (lane >= off) incl += n;
  }
  __shared__ int ws[8];
  if (lane == 63) ws[w] = incl;
  __syncthreads();
  int wo = 0;
  for (int ww = 0; ww < w; ++ww) wo += ws[ww];
  int excl = wo + incl - total;
  if (t < NB) Boff[t] = excl;
  if (t == NB - 1) Boff[NB] = excl + total;
}

__global__ __launch_bounds__(64) void k_bexp(const int* __restrict__ Hc,
                                             const int* __restrict__ Boff,
                                             int* __restrict__ G) {
  int b = blockIdx.x, l = threadIdx.x;
  int run = Boff[b];
  const int* p = Hc + b * NBLK_A;
  for (int c = 0; c < NBLK_A; c += 64) {
    int idx = c + l;
    int v = (idx < NBLK_A) ? p[idx] : 0;
    int incl = v;
    #pragma unroll
    for (int off = 1; off < 64; off <<= 1) {
      int n = __shfl_up(incl, off, 64);
      if (l >= off) incl += n;
    }
    if (idx < NBLK_A) G[b * NBLK_A + idx] = run + incl - v;
    run += __shfl(incl, 63, 64);
  }
}

__global__ __launch_bounds__(256) void k_bscat(const int* __restrict__ row,
                                               const int* __restrict__ col,
                                               const int* __restrict__ G,
                                               unsigned* __restrict__ tmp) {
  __shared__ int cur[NB];
  int b = blockIdx.x, t = threadIdx.x;
  for (int j = t; j < NB; j += 256) cur[j] = G[j * NBLK_A + b];
  __syncthreads();
  int base = b * CH;
  #pragma unroll
  for (int k = 0; k < 8; ++k) {
    int i = base + k * 1024 + t * 4;
    if (i < N_EDGES) {
      int4 r = *(const int4*)(row + i);
      int4 c = *(const int4*)(col + i);
      int p0 = atomicAdd(&cur[r.x >> 8], 1);
      tmp[p0] = (unsigned)c.x | ((unsigned)(r.x & 255) << 24);
      int p1 = atomicAdd(&cur[r.y >> 8], 1);
      tmp[p1] = (unsigned)c.y | ((unsigned)(r.y & 255) << 24);
      int p2 = atomicAdd(&cur[r.z >> 8], 1);
      tmp[p2] = (unsigned)c.z | ((unsigned)(r.z & 255) << 24);
      int p3 = atomicAdd(&cur[r.w >> 8], 1);
      tmp[p3] = (unsigned)c.w | ((unsigned)(r.w & 255) << 24);
    }
  }
}

__global__ __launch_bounds__(256) void k_bsort(const unsigned* __restrict__ tmp,
                                               const int* __restrict__ Boff,
                                               int* __restrict__ rp,
                                               int* __restrict__ cs) {
  __shared__ int hist[256];
  __shared__ int wsum[4];
  int b = blockIdx.x, t = threadIdx.x;
  int s = Boff[b], e = Boff[b + 1];
  hist[t] = 0;
  __syncthreads();
  for (int i = s + t; i < e; i += 256) atomicAdd(&hist[tmp[i] >> 24], 1);
  __syncthreads();
  int v = hist[t];
  int lane = t & 63, w = t >> 6;
  int incl = v;
  #pragma unroll
  for (int off = 1; off < 64; off <<= 1) {
    int n = __shfl_up(incl, off, 64);
    if (lane >= off) incl += n;
  }
  if (lane == 63) wsum[w] = incl;
  __syncthreads();
  int wo = 0;
  for (int ww = 0; ww < w; ++ww) wo += wsum[ww];
  int excl = s + wo + incl - v;
  int node = (b << 8) + t;
  if (node < N_NODES) rp[node] = excl;
  __syncthreads();
  hist[t] = excl;    // reuse as cursor
  __syncthreads();
  for (int i = s + t; i < e; i += 256) {
    unsigned u = tmp[i];
    int pos = atomicAdd(&hist[u >> 24], 1);
    cs[pos] = (int)(u & 0xFFFFFFu);
  }
  if (b == 0 && t == 0) rp[N_NODES] = N_EDGES;
}

// ---------------- prep: weight pack + x f32->bf16 (fused launch) ----------------

__global__ __launch_bounds__(256) void k_prep(const float* __restrict__ x,
                                              const float* __restrict__ Wl1,
                                              const float* __restrict__ Wr1,
                                              const float* __restrict__ Wl2,
                                              const float* __restrict__ Wr2,
                                              short* __restrict__ Bp1,
                                              short* __restrict__ Bp2,
                                              short* __restrict__ Acat) {
  if (blockIdx.x < 512) {
    int id = blockIdx.x * 256 + threadIdx.x;
    bool second = id >= 65536;
    int lid = id & 65535;
    int j = lid & 7;
    int lane = (lid >> 3) & 63;
    int blk = lid >> 9;
    int nb = blk & 15;
    int kk = blk >> 4;
    int k = kk * 32 + (lane >> 4) * 8 + j;
    int c = nb * 16 + (lane & 15);
    float v;
    if (!second) v = (k < 128) ? Wl1[k * 256 + c] : Wr1[(k - 128) * 256 + c];
    else         v = (c < 128) ? Wl2[k * 128 + c] : Wr2[k * 128 + (c - 128)];
    (second ? Bp2 : Bp1)[lid] = (short)f2bf(v);
  } else {
    int id = (blockIdx.x - 512) * 256 + threadIdx.x;
    if (id >= N_NODES * 32) return;
    int node = id >> 5, c4 = id & 31;
    float4 v = *(const float4*)(x + (size_t)node * 128 + c4 * 4);
    uint2 u;
    u.x = (unsigned)f2bf(v.x) | ((unsigned)f2bf(v.y) << 16);
    u.y = (unsigned)f2bf(v.z) | ((unsigned)f2bf(v.w) << 16);
    *(uint2*)(Acat + (size_t)node * 256 + 128 + c4 * 4) = u;
  }
}

// ---------------- aggregation (R7 version: measured 64.4 us) ----------------

template <bool RESID, int GOFF>
__global__ __launch_bounds__(256) void k_agg(const int* __restrict__ rp,
                                             const int* __restrict__ cs,
                                             const short* __restrict__ src,
                                             short* __restrict__ dst_bf,
                                             float* __restrict__ dst_f32) {
  const int t = __builtin_amdgcn_readfirstlane(blockIdx.x * 4 + (threadIdx.x >> 6));
  if (t >= N_NODES) return;
  const int lane = threadIdx.x & 63;
  const int s = rp[t], e = rp[t + 1];
  const int d = e - s;
  float a0 = 0.f, a1 = 0.f;
  const short* gb = src + GOFF + 2 * lane;
  if (d > 0) {
    const int last = e - 1;
    const int rounds = (d + 15) >> 4;
    for (int r = 0; r < rounds; ++r) {
      int base = s + (r << 4);
      unsigned u[16];
      #pragma unroll
      for (int q = 0; q < 16; ++q) {
        int j = base + q;
        j = (j < last) ? j : last;                       // wave-uniform clamp
        u[q] = *(const unsigned*)(gb + (size_t)cs[j] * 256);
      }
      #pragma unroll
      for (int q = 0; q < 16; ++q) {
        a0 += bf2f((unsigned short)u[q]);
        a1 += bf2f((unsigned short)(u[q] >> 16));
      }
    }
    const int over = (rounds << 4) - d;
    if (over) {
      unsigned ul = *(const unsigned*)(gb + (size_t)cs[last] * 256);
      float c = (float)over;
      a0 -= c * bf2f((unsigned short)ul);
      a1 -= c * bf2f((unsigned short)(ul >> 16));
    }
  }
  if (RESID) {
    unsigned r = *(const unsigned*)(src + (size_t)t * 256 + 128 + 2 * lane);
    a0 += bf2f((unsigned short)r);
    a1 += bf2f((unsigned short)(r >> 16));
    float2 o = {a0, a1};
    *(float2*)(dst_f32 + (size_t)t * 128 + 2 * lane) = o;
  } else {
    *(unsigned*)(dst_bf + (size_t)t * 256 + 2 * lane) =
        (unsigned)f2bf(a0) | ((unsigned)f2bf(a1) << 16);
  }
}

// ---------------- fused double-GEMM ----------------

// Per 128-row tile: h = relu(Acat@Bp1 + bl1) staged in LDS (bf16, XOR-swizzled
// idx ^ ((row&7)<<3) to break the stride-256 bank conflict), then
// P = h@Bp2 (+bl2 on cols 128..255), written via LDS full-line stores.
// 512 threads = 8 waves (2 row x 4 col of 64x64 wave tiles) covering 128x256.
// Eliminates the 51 MB Hbuf HBM round-trip entirely.
__global__ __launch_bounds__(512) void k_gemm2(const short* __restrict__ A,
                                               const short* __restrict__ Bp1,
                                               const float* __restrict__ bl1,
                                               const short* __restrict__ Bp2,
                                               const float* __restrict__ bl2,
                                               short* __restrict__ P) {
  __shared__ short hb[128 * 256];          // 64 KB exactly
  const int rt = blockIdx.x;
  const int lane = threadIdx.x & 63;
  const int wave = threadIdx.x >> 6;       // 0..7
  const int wr = wave >> 2, wc = wave & 3;
  const int row0 = rt * 128 + wr * 64;
  const int colbase = wc * 64;
  const int arow = lane & 15;
  const int kgrp = lane >> 4;
  const int ccol = lane & 15;
  const int crow = (lane >> 4) * 4;

  f32x4 acc[4][4];
  const f32x4 zero = {0.f, 0.f, 0.f, 0.f};
  #pragma unroll
  for (int a = 0; a < 4; ++a)
    #pragma unroll
    for (int b = 0; b < 4; ++b) acc[a][b] = zero;

  // ---- GEMM1: h = A @ Bp1 ----
  const short* Bbase1 = Bp1 + (size_t)lane * 8;
  for (int kk = 0; kk < 8; ++kk) {
    short8 af[4], bfr[4];
    const int kb = kk * 32 + kgrp * 8;
    #pragma unroll
    for (int mi = 0; mi < 4; ++mi)
      af[mi] = *(const short8*)(A + (size_t)(row0 + mi * 16 + arow) * 256 + kb);
    #pragma unroll
    for (int ni = 0; ni < 4; ++ni) {
      int nb = wc * 4 + ni;
      bfr[ni] = *(const short8*)(Bbase1 + ((size_t)(kk * 16 + nb) << 9));
    }
    #pragma unroll
    for (int mi = 0; mi < 4; ++mi)
      #pragma unroll
      for (int ni = 0; ni < 4; ++ni)
        acc[mi][ni] = __builtin_amdgcn_mfma_f32_16x16x32_bf16(af[mi], bfr[ni],
                                                              acc[mi][ni], 0, 0, 0);
  }

  // bias + relu -> swizzled LDS bf16
  #pragma unroll
  for (int ni = 0; ni < 4; ++ni) {
    const int colg = colbase + ni * 16 + ccol;
    const float bv = bl1[colg];
    #pragma unroll
    for (int mi = 0; mi < 4; ++mi) {
      #pragma unroll
      for (int j = 0; j < 4; ++j) {
        const int lrow = wr * 64 + mi * 16 + crow + j;
        float v = fmaxf(acc[mi][ni][j] + bv, 0.0f);
        hb[(lrow * 256 + colg) ^ ((lrow & 7) << 3)] = (short)f2bf(v);
      }
    }
  }
  __syncthreads();

  // ---- GEMM2: P = h @ Bp2 ----
  #pragma unroll
  for (int a = 0; a < 4; ++a)
    #pragma unroll
    for (int b = 0; b < 4; ++b) acc[a][b] = zero;
  const short* Bbase2 = Bp2 + (size_t)lane * 8;
  for (int kk = 0; kk < 8; ++kk) {
    short8 af[4], bfr[4];
    const int kb = kk * 32 + kgrp * 8;
    #pragma unroll
    for (int mi = 0; mi < 4; ++mi) {
      const int lrow = wr * 64 + mi * 16 + arow;
      af[mi] = *(const short8*)&hb[(lrow * 256 + kb) ^ ((lrow & 7) << 3)];
    }
    #pragma unroll
    for (int ni = 0; ni < 4; ++ni) {
      int nb = wc * 4 + ni;
      bfr[ni] = *(const short8*)(Bbase2 + ((size_t)(kk * 16 + nb) << 9));
    }
    #pragma unroll
    for (int mi = 0; mi < 4; ++mi)
      #pragma unroll
      for (int ni = 0; ni < 4; ++ni)
        acc[mi][ni] = __builtin_amdgcn_mfma_f32_16x16x32_bf16(af[mi], bfr[ni],
                                                              acc[mi][ni], 0, 0, 0);
  }
  __syncthreads();   // everyone done reading h before overwrite

  // bias2 (right half only) -> swizzled LDS bf16
  #pragma unroll
  for (int ni = 0; ni < 4; ++ni) {
    const int colg = colbase + ni * 16 + ccol;
    const float bv = (colg < 128) ? 0.f : bl2[colg - 128];
    #pragma unroll
    for (int mi = 0; mi < 4; ++mi) {
      #pragma unroll
      for (int j = 0; j < 4; ++j) {
        const int lrow = wr * 64 + mi * 16 + crow + j;
        float v = acc[mi][ni][j] + bv;
        hb[(lrow * 256 + colg) ^ ((lrow & 7) << 3)] = (short)f2bf(v);
      }
    }
  }
  __syncthreads();

  // cooperative full-line store: 32 groups x 8 shorts = one 512 B row
  const int grp = threadIdx.x & 31;
  const int rb = threadIdx.x >> 5;         // 0..15
  #pragma unroll
  for (int pp = 0; pp < 8; ++pp) {
    const int r = pp * 16 + rb;
    uint4 v4 = *(const uint4*)&hb[(r * 256 + grp * 8) ^ ((r & 7) << 3)];
    *(uint4*)(P + (size_t)(rt * 128 + r) * 256 + grp * 8) = v4;
  }
}

extern "C" void kernel_launch(void* const* d_in, const int* in_sizes, int n_in,
                              void* d_out, int out_size, void* d_ws, size_t ws_size,
                              hipStream_t stream) {
  const float* x   = (const float*)d_in[0];
  const int*   row = (const int*)d_in[1];
  const int*   col = (const int*)d_in[2];
  const float* Wl1 = (const float*)d_in[3];
  const float* bl1 = (const float*)d_in[4];
  const float* Wr1 = (const float*)d_in[5];
  const float* Wl2 = (const float*)d_in[6];
  const float* bl2 = (const float*)d_in[7];
  const float* Wr2 = (const float*)d_in[8];
  float* out = (float*)d_out;

  char* w = (char*)d_ws;
  auto alloc = [&](size_t bytes) {
    char* p = w;
    w += (bytes + 255) & ~(size_t)255;
    return p;
  };
  short* Acat = (short*)alloc((size_t)MPAD * 256 * 2);  // [agg_x_bf16 | x_bf16]
  short* P    = (short*)alloc((size_t)MPAD * 256 * 2);  // [h@Wl2 | h@Wr2+bl2], bf16
  short* Bp1  = (short*)alloc(65536 * 2);               // [Wl1;Wr1] packed (vcat)
  short* Bp2  = (short*)alloc(65536 * 2);               // [Wl2|Wr2] packed (hcat)
  int* rp   = (int*)alloc((N_NODES + 1) * 4);
  int* cs   = (int*)alloc((size_t)N_EDGES * 4);
  unsigned* tmp = (unsigned*)alloc((size_t)N_EDGES * 4);
  int* Hc   = (int*)alloc((size_t)NB * NBLK_A * 4);
  int* G    = (int*)alloc((size_t)NB * NBLK_A * 4);
  int* Boff = (int*)alloc((NB + 1) * 4);

  // --- CSR build: two-level counting sort (no global data atomics) ---
  k_bhist<<<NBLK_A, 256, 0, stream>>>(row, Hc);
  k_bscan<<<1, 512, 0, stream>>>(Hc, Boff);
  k_bexp<<<NB, 64, 0, stream>>>(Hc, Boff, G);
  k_bscat<<<NBLK_A, 256, 0, stream>>>(row, col, G, tmp);
  k_bsort<<<NB, 256, 0, stream>>>(tmp, Boff, rp, cs);

  // --- fused weight packing + x conversion (independent of CSR) ---
  k_prep<<<512 + (N_NODES * 32 + 255) / 256, 256, 0, stream>>>(
      x, Wl1, Wr1, Wl2, Wr2, Bp1, Bp2, Acat);

  // --- layer 1 agg ---
  k_agg<false, 128><<<(N_NODES + 3) / 4, 256, 0, stream>>>(
      rp, cs, Acat, Acat, nullptr);

  // --- fused double GEMM: P = relu(Acat@Bp1+bl1)@Bp2 (+bl2 right half) ---
  k_gemm2<<<MTILES, 512, 0, stream>>>(Acat, Bp1, bl1, Bp2, bl2, P);

  // --- layer 2 agg + residual -> out ---
  k_agg<true, 0><<<(N_NODES + 3) / 4, 256, 0, stream>>>(
      rp, cs, P, nullptr, out);
}